// Round 4
// baseline (326.959 us; speedup 1.0000x reference)
//
#include <hip/hip_runtime.h>
#include <stdint.h>

// ---------------------------------------------------------------------------
// Gemma3 block: QKV proj -> per-head RMSNorm -> RoPE -> sliding-window (512)
// causal attention -> out proj.  B=2, T=2048, D=2048, H=16, Hkv=4, Dh=128.
// All GEMM/attention math in bf16 MFMA (fp32 accum); softmax/norm/rope fp32.
// R3/R4: GEMM staging via global_load_lds width=16 (m97 lever), swizzle
// moved to the per-lane GLOBAL source address (LDS dest must stay linear).
// ---------------------------------------------------------------------------

typedef __attribute__((ext_vector_type(8))) short bf16x8;   // 8 bf16 = 4 VGPR
typedef __attribute__((ext_vector_type(4))) float f32x4;

typedef __attribute__((address_space(3))) unsigned int lds_u32;
typedef const __attribute__((address_space(1))) unsigned int glb_u32;

#define LOG2E 1.44269504088896340736f

__device__ __forceinline__ unsigned short f2bf(float f) {
  unsigned int x = __builtin_bit_cast(unsigned int, f);
  x += 0x7FFFu + ((x >> 16) & 1u);            // round-nearest-even
  return (unsigned short)(x >> 16);
}

// ---- fused fp32 -> bf16 casts for all 5 inputs, float4-vectorized ----------
// ranges (in float4 units): x 2097152 | Wq 1048576 | Wk 262144 | Wv 262144
//                           | Wo 1048576  => total 4718592 (grid-exact)
__global__ __launch_bounds__(256) void castall(const float* __restrict__ x,
                                               const float* __restrict__ wq,
                                               const float* __restrict__ wk,
                                               const float* __restrict__ wv,
                                               const float* __restrict__ wo,
                                               unsigned short* __restrict__ xb,
                                               unsigned short* __restrict__ wqkvb,
                                               unsigned short* __restrict__ wob) {
  int i = blockIdx.x * 256 + threadIdx.x;
  const float* src;
  unsigned short* dst;
  int off;
  if (i < 2097152)       { src = x;  dst = xb;              off = i; }
  else if (i < 3145728)  { src = wq; dst = wqkvb;           off = i - 2097152; }
  else if (i < 3407872)  { src = wk; dst = wqkvb + 4194304; off = i - 3145728; }
  else if (i < 3670016)  { src = wv; dst = wqkvb + 5242880; off = i - 3407872; }
  else                   { src = wo; dst = wob;             off = i - 3670016; }
  float4 v = ((const float4*)src)[off];
  uint2 o;
  o.x = (unsigned)f2bf(v.x) | ((unsigned)f2bf(v.y) << 16);
  o.y = (unsigned)f2bf(v.z) | ((unsigned)f2bf(v.w) << 16);
  ((uint2*)dst)[off] = o;
}

// ---- RoPE cos/sin table [T=2048][64] ---------------------------------------
__global__ __launch_bounds__(256) void rope_tab(float* __restrict__ c,
                                                float* __restrict__ s) {
  int idx = blockIdx.x * 256 + threadIdx.x;    // T*64 = 131072
  int t = idx >> 6, i = idx & 63;
  // inv_freq[i] = 10000^(-i/64) = 2^(-i/64 * log2(10000))
  float invf = exp2f(-(float)i * (13.287712379549449f / 64.0f));
  float a = (float)t * invf;
  c[idx] = cosf(a);
  s[idx] = sinf(a);
}

// ---- bf16 GEMM, C[M,N] = A[M,K] * B[N,K]^T, fp32 out -----------------------
// 128x128 tile, BK=64, 4 waves (2x2), 16x16x32 MFMA.
// Staging: global_load_lds dwordx4. LDS dest linear (wave base + lane*16);
// the st-swizzle is applied to the per-lane GLOBAL chunk index instead:
// slot s of row r holds global chunk s^(r&7)  (r&7 == lane>>3 per 8-row seg).
// Fragment reads then use byte_off = (chunk*16) ^ ((row&7)<<4) as before.
__global__ __launch_bounds__(256) void gemm_bt(const unsigned short* __restrict__ A,
                                               const unsigned short* __restrict__ B,
                                               float* __restrict__ C,
                                               int N, int K) {
  __shared__ uint8_t As[128 * 128];   // 128 rows x 64 bf16 (128B), swizzled
  __shared__ uint8_t Bs[128 * 128];
  const int tid = threadIdx.x;
  const int lane = tid & 63;
  const int w = tid >> 6, wr = w >> 1, wc = w & 1;
  const int m0 = blockIdx.y * 128, n0 = blockIdx.x * 128;

  // per-lane source permutation for the 1KB (8-row) wave segment
  const int srow = lane >> 3;                  // row within segment (== row&7)
  const int schunk = (lane & 7) ^ srow;        // global 16B-chunk within row

  f32x4 acc[4][4];
#pragma unroll
  for (int i = 0; i < 4; ++i)
#pragma unroll
    for (int j = 0; j < 4; ++j) acc[i][j] = f32x4{0.f, 0.f, 0.f, 0.f};

  for (int kk = 0; kk < K; kk += 64) {
    __syncthreads();                 // previous tile's reads complete
#pragma unroll
    for (int i = 0; i < 4; ++i) {    // 4 A-segs + 4 B-segs per wave (1KB each)
      int r0 = w * 32 + i * 8;       // first row of this segment
      const unsigned short* ag =
          A + (size_t)(m0 + r0 + srow) * K + kk + schunk * 8;
      __builtin_amdgcn_global_load_lds((glb_u32*)ag,
                                       (lds_u32*)(As + r0 * 128), 16, 0, 0);
      const unsigned short* bg =
          B + (size_t)(n0 + r0 + srow) * K + kk + schunk * 8;
      __builtin_amdgcn_global_load_lds((glb_u32*)bg,
                                       (lds_u32*)(Bs + r0 * 128), 16, 0, 0);
    }
    __syncthreads();                 // drains vmcnt(0): tiles visible
#pragma unroll
    for (int ks = 0; ks < 2; ++ks) { // two K=32 steps per BK=64
      bf16x8 af[4], bfr[4];
#pragma unroll
      for (int mf = 0; mf < 4; ++mf) {
        int row = wr * 64 + mf * 16 + (lane & 15);
        int bo = ks * 64 + (lane >> 4) * 16;
        af[mf] = *(const bf16x8*)(As + row * 128 + (bo ^ ((row & 7) << 4)));
      }
#pragma unroll
      for (int nf = 0; nf < 4; ++nf) {
        int row = wc * 64 + nf * 16 + (lane & 15);
        int bo = ks * 64 + (lane >> 4) * 16;
        bfr[nf] = *(const bf16x8*)(Bs + row * 128 + (bo ^ ((row & 7) << 4)));
      }
#pragma unroll
      for (int mf = 0; mf < 4; ++mf)
#pragma unroll
        for (int nf = 0; nf < 4; ++nf)
          acc[mf][nf] = __builtin_amdgcn_mfma_f32_16x16x32_bf16(
              af[mf], bfr[nf], acc[mf][nf], 0, 0, 0);
    }
  }
  // C/D layout: col = lane&15, row = (lane>>4)*4 + reg  [m89-verified]
#pragma unroll
  for (int mf = 0; mf < 4; ++mf)
#pragma unroll
    for (int nf = 0; nf < 4; ++nf) {
      int row = m0 + wr * 64 + mf * 16 + (lane >> 4) * 4;
      int col = n0 + wc * 64 + nf * 16 + (lane & 15);
#pragma unroll
      for (int r = 0; r < 4; ++r)
        C[(size_t)(row + r) * N + col] = acc[mf][nf][r];
    }
}

// ---- RMSNorm + RoPE + scale epilogue (Q and K heads) -----------------------
// One block per (b,t) row of qkv_f32 [4096][3072]. 4 waves:
//   each wave: 4 Q heads + 1 K head (64 lanes x 2 elems over Dh=128).
__global__ __launch_bounds__(256) void eplg(const float* __restrict__ qkv,
                                            const float* __restrict__ qw,
                                            const float* __restrict__ kw,
                                            const float* __restrict__ rc,
                                            const float* __restrict__ rs,
                                            unsigned short* __restrict__ qb,
                                            unsigned short* __restrict__ kb) {
  const int row = blockIdx.x;                 // b*2048 + t
  const int t = row & 2047;
  const int lane = threadIdx.x & 63, w = threadIdx.x >> 6;
  const float* base = qkv + (size_t)row * 3072;
  const int d0 = 2 * lane;
  const float c0 = rc[t * 64 + (d0 & 63)];
  const float c1 = rc[t * 64 + ((d0 + 1) & 63)];
  const float s0 = rs[t * 64 + (d0 & 63)];
  const float s1 = rs[t * 64 + ((d0 + 1) & 63)];
  const float sgn = (lane < 32) ? -1.0f : 1.0f;   // rotate_half sign

#pragma unroll
  for (int hh = 0; hh < 4; ++hh) {
    int h = w * 4 + hh;
    float2 x = *(const float2*)(base + h * 128 + d0);
    float ss = x.x * x.x + x.y * x.y;
#pragma unroll
    for (int m = 1; m < 64; m <<= 1) ss += __shfl_xor(ss, m);
    float r = rsqrtf(ss * (1.0f / 128.0f) + 1e-6f);
    float y0 = x.x * r * (1.0f + qw[d0]);
    float y1 = x.y * r * (1.0f + qw[d0 + 1]);
    float p0 = __shfl_xor(y0, 32);              // partner d +/- 64
    float p1 = __shfl_xor(y1, 32);
    float o0 = (y0 * c0 + sgn * p0 * s0) * 0.08838834764831845f;  // *Dh^-0.5
    float o1 = (y1 * c1 + sgn * p1 * s1) * 0.08838834764831845f;
    unsigned int pk = (unsigned)f2bf(o0) | ((unsigned)f2bf(o1) << 16);
    *(unsigned int*)(qb + (size_t)row * 2048 + h * 128 + d0) = pk;
  }
  {
    // K head = wave index
    float2 x = *(const float2*)(base + 2048 + w * 128 + d0);
    float ss = x.x * x.x + x.y * x.y;
#pragma unroll
    for (int m = 1; m < 64; m <<= 1) ss += __shfl_xor(ss, m);
    float r = rsqrtf(ss * (1.0f / 128.0f) + 1e-6f);
    float y0 = x.x * r * (1.0f + kw[d0]);
    float y1 = x.y * r * (1.0f + kw[d0 + 1]);
    float p0 = __shfl_xor(y0, 32);
    float p1 = __shfl_xor(y1, 32);
    float o0 = y0 * c0 + sgn * p0 * s0;
    float o1 = y1 * c1 + sgn * p1 * s1;
    unsigned int pk = (unsigned)f2bf(o0) | ((unsigned)f2bf(o1) << 16);
    *(unsigned int*)(kb + (size_t)row * 512 + w * 128 + d0) = pk;
  }
}

// ---- V transpose: qkvf v-cols -> vbt[b*512 + d][t] bf16, 64x64 LDS tiles ---
__global__ __launch_bounds__(256) void vtrans(const float* __restrict__ qkvf,
                                              unsigned short* __restrict__ vbt) {
  __shared__ float tile[64][65];               // +1 pad: conflict-free
  const int t0 = blockIdx.x * 64;              // 32 tiles over T
  const int d0 = blockIdx.y * 64;              // 8 tiles over 512 v-dims
  const int b = blockIdx.z;
  const int tid = threadIdx.x;
#pragma unroll
  for (int i = 0; i < 4; ++i) {
    int idx = tid + 256 * i;                   // 0..1023
    int r = idx >> 4, c4 = idx & 15;           // 64 t-rows x 16 float4
    float4 v = *(const float4*)(qkvf + (size_t)(b * 2048 + t0 + r) * 3072 +
                                2560 + d0 + c4 * 4);
    tile[r][c4 * 4 + 0] = v.x;
    tile[r][c4 * 4 + 1] = v.y;
    tile[r][c4 * 4 + 2] = v.z;
    tile[r][c4 * 4 + 3] = v.w;
  }
  __syncthreads();
  const int dr = tid >> 2, ts = (tid & 3) * 16;  // 64 dims x 4 t-segments
  unsigned short tmp[16];
#pragma unroll
  for (int j = 0; j < 16; ++j) tmp[j] = f2bf(tile[ts + j][dr]);
  uint4* dst = (uint4*)(vbt + (size_t)(b * 512 + d0 + dr) * 2048 + t0 + ts);
  dst[0] = *(uint4*)(tmp);
  dst[1] = *(uint4*)(tmp + 8);
}

// ---- flash attention, sliding window 512 -----------------------------------
// Grid (qtile=32, h=16, b=2); 4 waves; wave w owns q rows t0+16w..+15.
__global__ __launch_bounds__(256) void attn(const unsigned short* __restrict__ qb,
                                            const unsigned short* __restrict__ kb,
                                            const unsigned short* __restrict__ vbt,
                                            unsigned short* __restrict__ ctxb) {
  __shared__ uint8_t Ks[64 * 256];    // 64 keys x 128 bf16 (256B row), swz
  __shared__ uint8_t Vs[128 * 128];   // 128 dims x 64 bf16 (128B row), swz
  __shared__ uint8_t Ps[4][16 * 128]; // per-wave P: 16 rows x 64 bf16, swz
  const int qi = blockIdx.x, h = blockIdx.y, b = blockIdx.z;
  const int kvh = h >> 2;
  const int t0 = qi * 64;
  const int tid = threadIdx.x, lane = tid & 63, w = tid >> 6;

  // Q fragments live in registers the whole kernel (A-operand layout:
  // row = lane&15, k = (lane>>4)*8 .. +8)
  bf16x8 qf[4];
  {
    int qrow = t0 + w * 16 + (lane & 15);
    const unsigned short* qp =
        qb + (size_t)(b * 2048 + qrow) * 2048 + h * 128 + (lane >> 4) * 8;
#pragma unroll
    for (int kc = 0; kc < 4; ++kc) qf[kc] = *(const bf16x8*)(qp + kc * 32);
  }
  f32x4 of[8];
#pragma unroll
  for (int i = 0; i < 8; ++i) of[i] = f32x4{0.f, 0.f, 0.f, 0.f};
  float m_run[4], l_run[4];
#pragma unroll
  for (int r = 0; r < 4; ++r) { m_run[r] = -1e30f; l_run[r] = 0.0f; }

  int kt0 = t0 - 512; if (kt0 < 0) kt0 = 0;
  const int nt = (t0 + 64 - kt0) >> 6;          // <= 9 key tiles
  uint8_t* Pw = Ps[w];

  for (int it = 0; it < nt; ++it) {
    const int kt = kt0 + (it << 6);
    __syncthreads();
#pragma unroll
    for (int i = 0; i < 4; ++i) {               // stage K (16KB) + V (16KB)
      int c = tid + 256 * i;
      int krow = c >> 4, kcin = c & 15;
      uint4 kv = *(const uint4*)(kb + (size_t)(b * 2048 + kt + krow) * 512 +
                                 kvh * 128 + kcin * 8);
      *(uint4*)(Ks + krow * 256 + ((kcin * 16) ^ ((krow & 7) << 4))) = kv;
      int vrow = c >> 3, vcin = c & 7;
      uint4 vv = *(const uint4*)(vbt + (size_t)(b * 512 + kvh * 128 + vrow) * 2048 +
                                 kt + vcin * 8);
      *(uint4*)(Vs + vrow * 128 + ((vcin * 16) ^ ((vrow & 7) << 4))) = vv;
    }
    __syncthreads();

    // S = Q K^T : 16 q-rows x 64 keys per wave
    f32x4 sf[4];
#pragma unroll
    for (int nc = 0; nc < 4; ++nc) {
      f32x4 s = f32x4{0.f, 0.f, 0.f, 0.f};
      int key = nc * 16 + (lane & 15);
#pragma unroll
      for (int kc = 0; kc < 4; ++kc) {
        bf16x8 kf = *(const bf16x8*)(
            Ks + key * 256 + (((lane >> 4) * 16 + kc * 64) ^ ((key & 7) << 4)));
        s = __builtin_amdgcn_mfma_f32_16x16x32_bf16(qf[kc], kf, s, 0, 0, 0);
      }
      sf[nc] = s;
    }
    // mask: j <= t and t - j <= 512
#pragma unroll
    for (int nc = 0; nc < 4; ++nc) {
      int j = kt + nc * 16 + (lane & 15);
#pragma unroll
      for (int r = 0; r < 4; ++r) {
        int tq = t0 + w * 16 + (lane >> 4) * 4 + r;
        if (!((j <= tq) && (tq - j <= 512))) sf[nc][r] = -1e30f;
      }
    }
    // online softmax (16-lane groups hold one row's 16 keys)
    float alpha[4];
#pragma unroll
    for (int r = 0; r < 4; ++r) {
      float mx = fmaxf(fmaxf(sf[0][r], sf[1][r]), fmaxf(sf[2][r], sf[3][r]));
      mx = fmaxf(mx, __shfl_xor(mx, 1));
      mx = fmaxf(mx, __shfl_xor(mx, 2));
      mx = fmaxf(mx, __shfl_xor(mx, 4));
      mx = fmaxf(mx, __shfl_xor(mx, 8));
      float mn = fmaxf(m_run[r], mx);
      alpha[r] = exp2f((m_run[r] - mn) * LOG2E);
      m_run[r] = mn;
    }
    float l_add[4] = {0.f, 0.f, 0.f, 0.f};
#pragma unroll
    for (int nc = 0; nc < 4; ++nc)
#pragma unroll
      for (int r = 0; r < 4; ++r) {
        float p = exp2f((sf[nc][r] - m_run[r]) * LOG2E);
        sf[nc][r] = p;
        l_add[r] += p;
      }
#pragma unroll
    for (int r = 0; r < 4; ++r) {
      float la = l_add[r];
      la += __shfl_xor(la, 1);
      la += __shfl_xor(la, 2);
      la += __shfl_xor(la, 4);
      la += __shfl_xor(la, 8);
      l_run[r] = l_run[r] * alpha[r] + la;
    }
#pragma unroll
    for (int i = 0; i < 8; ++i)
#pragma unroll
      for (int r = 0; r < 4; ++r) of[i][r] *= alpha[r];

    // P -> LDS (per-wave, bf16, swizzled) to repack into A-operand layout
#pragma unroll
    for (int nc = 0; nc < 4; ++nc) {
      int key = nc * 16 + (lane & 15);
#pragma unroll
      for (int r = 0; r < 4; ++r) {
        int prow = (lane >> 4) * 4 + r;
        *(unsigned short*)(Pw + prow * 128 + ((key * 2) ^ ((prow & 7) << 4))) =
            f2bf(sf[nc][r]);
      }
    }
    // O += P V  (A = P[16 x 64], B-frag from transposed V in LDS)
#pragma unroll
    for (int ks = 0; ks < 2; ++ks) {
      int prow = lane & 15;
      bf16x8 pf = *(const bf16x8*)(
          Pw + prow * 128 + ((ks * 64 + (lane >> 4) * 16) ^ ((prow & 7) << 4)));
#pragma unroll
      for (int nc8 = 0; nc8 < 8; ++nc8) {
        int vrow = nc8 * 16 + (lane & 15);
        bf16x8 vf = *(const bf16x8*)(
            Vs + vrow * 128 + ((ks * 64 + (lane >> 4) * 16) ^ ((vrow & 7) << 4)));
        of[nc8] = __builtin_amdgcn_mfma_f32_16x16x32_bf16(pf, vf, of[nc8], 0, 0, 0);
      }
    }
  }
  // normalize + store ctx (bf16, row-major [B*T][H*Dh])
#pragma unroll
  for (int nc8 = 0; nc8 < 8; ++nc8)
#pragma unroll
    for (int r = 0; r < 4; ++r) {
      int tq = t0 + w * 16 + (lane >> 4) * 4 + r;
      int col = h * 128 + nc8 * 16 + (lane & 15);
      ctxb[(size_t)(b * 2048 + tq) * 2048 + col] = f2bf(of[nc8][r] / l_run[r]);
    }
}

// ---------------------------------------------------------------------------
extern "C" void kernel_launch(void* const* d_in, const int* in_sizes, int n_in,
                              void* d_out, int out_size, void* d_ws, size_t ws_size,
                              hipStream_t stream) {
  const float* x  = (const float*)d_in[0];   // [2,2048,2048]
  const float* Wq = (const float*)d_in[1];   // [2048,2048]
  const float* Wk = (const float*)d_in[2];   // [512,2048]
  const float* Wv = (const float*)d_in[3];   // [512,2048]
  const float* Wo = (const float*)d_in[4];   // [2048,2048]
  const float* qw = (const float*)d_in[5];   // [128]
  const float* kw = (const float*)d_in[6];   // [128]

  uint8_t* ws = (uint8_t*)d_ws;
  if (ws_size < 131072000ull) return;        // need ~125 MB scratch
  unsigned short* xb    = (unsigned short*)(ws);               // 16.8 MB
  unsigned short* wqkvb = (unsigned short*)(ws + 16777216);    // 12.6 MB
  unsigned short* wob   = (unsigned short*)(ws + 29360128);    //  8.4 MB
  float*          qkvf  = (float*)(ws + 37748736);             // 50.3 MB
  unsigned short* qb2   = (unsigned short*)(ws + 88080384);    // 16.8 MB
  unsigned short* kb2   = (unsigned short*)(ws + 104857600);   //  4.2 MB
  unsigned short* vbt   = (unsigned short*)(ws + 109051904);   //  4.2 MB
  unsigned short* ctxb  = (unsigned short*)(ws + 113246208);   // 16.8 MB
  float*          ropec = (float*)(ws + 130023424);            //  0.5 MB
  float*          ropes = (float*)(ws + 130547712);            //  0.5 MB

  // 1) all input casts to bf16 (one fused launch)
  castall<<<18432, 256, 0, stream>>>(x, Wq, Wk, Wv, Wo, xb, wqkvb, wob);
  // 2) rope table
  rope_tab<<<512, 256, 0, stream>>>(ropec, ropes);
  // 3) fused QKV GEMM: [4096,2048] x [3072,2048]^T -> fp32 [4096,3072]
  {
    dim3 g(3072 / 128, 4096 / 128);
    gemm_bt<<<g, 256, 0, stream>>>(xb, wqkvb, qkvf, 3072, 2048);
  }
  // 4) RMSNorm + RoPE + scale (Q, K)
  eplg<<<4096, 256, 0, stream>>>(qkvf, qw, kw, ropec, ropes, qb2, kb2);
  // 5) V transpose (tiled, coalesced)
  {
    dim3 g(32, 8, 2);
    vtrans<<<g, 256, 0, stream>>>(qkvf, vbt);
  }
  // 6) sliding-window attention
  {
    dim3 g(32, 16, 2);
    attn<<<g, 256, 0, stream>>>(qb2, kb2, vbt, ctxb);
  }
  // 7) output projection: [4096,2048] x [2048,2048]^T -> fp32 d_out
  {
    dim3 g(2048 / 128, 4096 / 128);
    gemm_bt<<<g, 256, 0, stream>>>(ctxb, wob, (float*)d_out, 2048, 2048);
  }
}

// Round 6
// 294.519 us; speedup vs baseline: 1.1101x; 1.1101x over previous
//
#include <hip/hip_runtime.h>
#include <stdint.h>

// ---------------------------------------------------------------------------
// Gemma3 block: QKV proj -> per-head RMSNorm -> RoPE -> sliding-window (512)
// causal attention -> out proj.  B=2, T=2048, D=2048, H=16, Hkv=4, Dh=128.
// R6: R5's counted-vmcnt 256-row GEMM pipeline, with the LDS slot-pointer
// arrays (illegal static addrspacecast init) replaced by runtime arithmetic.
// ---------------------------------------------------------------------------

typedef __attribute__((ext_vector_type(8))) short bf16x8;   // 8 bf16 = 4 VGPR
typedef __attribute__((ext_vector_type(4))) float f32x4;

typedef __attribute__((address_space(3))) unsigned int lds_u32;
typedef const __attribute__((address_space(1))) unsigned int glb_u32;

#define LOG2E 1.44269504088896340736f

__device__ __forceinline__ unsigned short f2bf(float f) {
  unsigned int x = __builtin_bit_cast(unsigned int, f);
  x += 0x7FFFu + ((x >> 16) & 1u);            // round-nearest-even
  return (unsigned short)(x >> 16);
}

// ---- fused fp32 -> bf16 casts for all 5 inputs, float4-vectorized ----------
__global__ __launch_bounds__(256) void castall(const float* __restrict__ x,
                                               const float* __restrict__ wq,
                                               const float* __restrict__ wk,
                                               const float* __restrict__ wv,
                                               const float* __restrict__ wo,
                                               unsigned short* __restrict__ xb,
                                               unsigned short* __restrict__ wqkvb,
                                               unsigned short* __restrict__ wob) {
  int i = blockIdx.x * 256 + threadIdx.x;
  const float* src;
  unsigned short* dst;
  int off;
  if (i < 2097152)       { src = x;  dst = xb;              off = i; }
  else if (i < 3145728)  { src = wq; dst = wqkvb;           off = i - 2097152; }
  else if (i < 3407872)  { src = wk; dst = wqkvb + 4194304; off = i - 3145728; }
  else if (i < 3670016)  { src = wv; dst = wqkvb + 5242880; off = i - 3407872; }
  else                   { src = wo; dst = wob;             off = i - 3670016; }
  float4 v = ((const float4*)src)[off];
  uint2 o;
  o.x = (unsigned)f2bf(v.x) | ((unsigned)f2bf(v.y) << 16);
  o.y = (unsigned)f2bf(v.z) | ((unsigned)f2bf(v.w) << 16);
  ((uint2*)dst)[off] = o;
}

// ---- RoPE cos/sin table [T=2048][64] ---------------------------------------
__global__ __launch_bounds__(256) void rope_tab(float* __restrict__ c,
                                                float* __restrict__ s) {
  int idx = blockIdx.x * 256 + threadIdx.x;    // T*64 = 131072
  int t = idx >> 6, i = idx & 63;
  float invf = exp2f(-(float)i * (13.287712379549449f / 64.0f));
  float a = (float)t * invf;
  c[idx] = cosf(a);
  s[idx] = sinf(a);
}

// ---- bf16 GEMM, C[M,N] = A[M,K]*B[N,K]^T, fp32 out -------------------------
// BM=256 x BN(256|128), BK=64, 512 thr = 8 waves (2M x 4N), wave C = 128 x BN/4.
// Double-buffered LDS ring; per K-tile:
//   [stage A(t+1)] vmcnt(4) BAR [kh0 reads+MFMA] [stage B(t+1)] [kh1] BAR
// vmcnt(4) leaves the newest 4 loads (A(t+1)) in flight => B(t)/A(t) landed.
// Slot-overwrite safety: issue in phase p targets the slot last read in
// phase p-2; the p-1 barrier orders all reads (lgkm'd pre-barrier) first.
// LDS per slot: [rows][64 bf16], byte = r*128 + ((chunk ^ (r&7))<<4) -- the
// R2-proven zero-conflict swizzle; global_load_lds writes linearly, so the
// inverse permutation is applied to the per-lane GLOBAL source chunk.
template <int BN>
__global__ __launch_bounds__(512, 2) void gemm256(const unsigned short* __restrict__ A,
                                                  const unsigned short* __restrict__ Bm,
                                                  float* __restrict__ C,
                                                  int N, int K) {
  constexpr int BSL = BN * 128;               // B slot bytes
  __shared__ uint8_t lds[65536 + 2 * BSL];    // [A0|A1|B0|B1]
  const int tid = threadIdx.x, lane = tid & 63, w = tid >> 6;
  const int wm = w >> 2, wn = w & 3;
  const size_t m0 = (size_t)blockIdx.y * 256, n0 = (size_t)blockIdx.x * BN;
  const int srow = lane >> 3;                 // row within 8-row wave segment
  const int schunk = (lane & 7) ^ srow;       // source 16B chunk (inv-swizzle)

  f32x4 acc[8][BN / 64];
#pragma unroll
  for (int i = 0; i < 8; ++i)
#pragma unroll
    for (int j = 0; j < BN / 64; ++j) acc[i][j] = f32x4{0.f, 0.f, 0.f, 0.f};

  const int NT = K >> 6;

  auto stageA = [&](int t, int par) {
    uint8_t* slot = lds + (par << 15);        // par * 32768
#pragma unroll
    for (int j = 0; j < 4; ++j) {             // 256 rows = 4 rounds x 64 rows
      int r0 = (j * 8 + w) * 8;
      const unsigned short* src =
          A + (m0 + r0 + srow) * (size_t)K + t * 64 + schunk * 8;
      __builtin_amdgcn_global_load_lds((glb_u32*)src,
                                       (lds_u32*)(slot + r0 * 128), 16, 0, 0);
    }
  };
  auto stageB = [&](int t, int par) {
    uint8_t* slot = lds + 65536 + par * BSL;
#pragma unroll
    for (int j = 0; j < BN / 64; ++j) {
      int r0 = (j * 8 + w) * 8;
      const unsigned short* src =
          Bm + (n0 + r0 + srow) * (size_t)K + t * 64 + schunk * 8;
      __builtin_amdgcn_global_load_lds((glb_u32*)src,
                                       (lds_u32*)(slot + r0 * 128), 16, 0, 0);
    }
  };
  auto compute = [&](int par, int h) {
    const uint8_t* Asl = lds + (par << 15);
    const uint8_t* Bsl = lds + 65536 + par * BSL;
    bf16x8 af[8], bf[BN / 64];
    const int x7 = lane & 7;
    const int cx = h * 4 + (lane >> 4);       // 16B chunk within 128B row
    const int rab = wm * 128 + (lane & 15);
    const int rbb = wn * (BN / 4) + (lane & 15);
#pragma unroll
    for (int mt = 0; mt < 8; ++mt)
      af[mt] = *(const bf16x8*)(Asl + (rab + mt * 16) * 128 + ((cx ^ x7) << 4));
#pragma unroll
    for (int nt = 0; nt < BN / 64; ++nt)
      bf[nt] = *(const bf16x8*)(Bsl + (rbb + nt * 16) * 128 + ((cx ^ x7) << 4));
    __builtin_amdgcn_s_setprio(1);
#pragma unroll
    for (int mt = 0; mt < 8; ++mt)
#pragma unroll
      for (int nt = 0; nt < BN / 64; ++nt)
        acc[mt][nt] = __builtin_amdgcn_mfma_f32_16x16x32_bf16(
            af[mt], bf[nt], acc[mt][nt], 0, 0, 0);
    __builtin_amdgcn_s_setprio(0);
  };

  // prologue: tile 0 into parity 0
  stageA(0, 0);
  stageB(0, 0);
  for (int t = 0; t < NT - 1; ++t) {
    const int p = t & 1, q = p ^ 1;
    stageA(t + 1, q);
    asm volatile("s_waitcnt vmcnt(4)" ::: "memory");
    __builtin_amdgcn_s_barrier();
    __builtin_amdgcn_sched_barrier(0);        // keep reads after the barrier
    compute(p, 0);
    stageB(t + 1, q);
    compute(p, 1);
    asm volatile("" ::: "memory");
    __builtin_amdgcn_s_barrier();             // readers done before next stage
    __builtin_amdgcn_sched_barrier(0);
  }
  // tail tile (nothing left to stage -> full drain once)
  {
    const int p = (NT - 1) & 1;
    asm volatile("s_waitcnt vmcnt(0)" ::: "memory");
    __builtin_amdgcn_s_barrier();
    __builtin_amdgcn_sched_barrier(0);
    compute(p, 0);
    compute(p, 1);
  }
  // epilogue: C/D layout col = lane&15, row = (lane>>4)*4 + reg
#pragma unroll
  for (int mt = 0; mt < 8; ++mt)
#pragma unroll
    for (int nt = 0; nt < BN / 64; ++nt) {
      size_t row = m0 + wm * 128 + mt * 16 + (lane >> 4) * 4;
      size_t col = n0 + wn * (BN / 4) + nt * 16 + (lane & 15);
#pragma unroll
      for (int r = 0; r < 4; ++r)
        C[(row + r) * N + col] = acc[mt][nt][r];
    }
}

// ---- RMSNorm + RoPE + scale epilogue (Q and K heads) -----------------------
__global__ __launch_bounds__(256) void eplg(const float* __restrict__ qkv,
                                            const float* __restrict__ qw,
                                            const float* __restrict__ kw,
                                            const float* __restrict__ rc,
                                            const float* __restrict__ rs,
                                            unsigned short* __restrict__ qb,
                                            unsigned short* __restrict__ kb) {
  const int row = blockIdx.x;                 // b*2048 + t
  const int t = row & 2047;
  const int lane = threadIdx.x & 63, w = threadIdx.x >> 6;
  const float* base = qkv + (size_t)row * 3072;
  const int d0 = 2 * lane;
  const float c0 = rc[t * 64 + (d0 & 63)];
  const float c1 = rc[t * 64 + ((d0 + 1) & 63)];
  const float s0 = rs[t * 64 + (d0 & 63)];
  const float s1 = rs[t * 64 + ((d0 + 1) & 63)];
  const float sgn = (lane < 32) ? -1.0f : 1.0f;   // rotate_half sign

#pragma unroll
  for (int hh = 0; hh < 4; ++hh) {
    int h = w * 4 + hh;
    float2 x = *(const float2*)(base + h * 128 + d0);
    float ss = x.x * x.x + x.y * x.y;
#pragma unroll
    for (int m = 1; m < 64; m <<= 1) ss += __shfl_xor(ss, m);
    float r = rsqrtf(ss * (1.0f / 128.0f) + 1e-6f);
    float y0 = x.x * r * (1.0f + qw[d0]);
    float y1 = x.y * r * (1.0f + qw[d0 + 1]);
    float p0 = __shfl_xor(y0, 32);              // partner d +/- 64
    float p1 = __shfl_xor(y1, 32);
    float o0 = (y0 * c0 + sgn * p0 * s0) * 0.08838834764831845f;  // *Dh^-0.5
    float o1 = (y1 * c1 + sgn * p1 * s1) * 0.08838834764831845f;
    unsigned int pk = (unsigned)f2bf(o0) | ((unsigned)f2bf(o1) << 16);
    *(unsigned int*)(qb + (size_t)row * 2048 + h * 128 + d0) = pk;
  }
  {
    float2 x = *(const float2*)(base + 2048 + w * 128 + d0);
    float ss = x.x * x.x + x.y * x.y;
#pragma unroll
    for (int m = 1; m < 64; m <<= 1) ss += __shfl_xor(ss, m);
    float r = rsqrtf(ss * (1.0f / 128.0f) + 1e-6f);
    float y0 = x.x * r * (1.0f + kw[d0]);
    float y1 = x.y * r * (1.0f + kw[d0 + 1]);
    float p0 = __shfl_xor(y0, 32);
    float p1 = __shfl_xor(y1, 32);
    float o0 = y0 * c0 + sgn * p0 * s0;
    float o1 = y1 * c1 + sgn * p1 * s1;
    unsigned int pk = (unsigned)f2bf(o0) | ((unsigned)f2bf(o1) << 16);
    *(unsigned int*)(kb + (size_t)row * 512 + w * 128 + d0) = pk;
  }
}

// ---- V transpose: qkvf v-cols -> vbt[b*512 + d][t] bf16, 64x64 LDS tiles ---
__global__ __launch_bounds__(256) void vtrans(const float* __restrict__ qkvf,
                                              unsigned short* __restrict__ vbt) {
  __shared__ float tile[64][65];               // +1 pad: conflict-free
  const int t0 = blockIdx.x * 64;
  const int d0 = blockIdx.y * 64;
  const int b = blockIdx.z;
  const int tid = threadIdx.x;
#pragma unroll
  for (int i = 0; i < 4; ++i) {
    int idx = tid + 256 * i;                   // 0..1023
    int r = idx >> 4, c4 = idx & 15;
    float4 v = *(const float4*)(qkvf + (size_t)(b * 2048 + t0 + r) * 3072 +
                                2560 + d0 + c4 * 4);
    tile[r][c4 * 4 + 0] = v.x;
    tile[r][c4 * 4 + 1] = v.y;
    tile[r][c4 * 4 + 2] = v.z;
    tile[r][c4 * 4 + 3] = v.w;
  }
  __syncthreads();
  const int dr = tid >> 2, ts = (tid & 3) * 16;
  unsigned short tmp[16];
#pragma unroll
  for (int j = 0; j < 16; ++j) tmp[j] = f2bf(tile[ts + j][dr]);
  uint4* dst = (uint4*)(vbt + (size_t)(b * 512 + d0 + dr) * 2048 + t0 + ts);
  dst[0] = *(uint4*)(tmp);
  dst[1] = *(uint4*)(tmp + 8);
}

// ---- flash attention, sliding window 512 -----------------------------------
__global__ __launch_bounds__(256) void attn(const unsigned short* __restrict__ qb,
                                            const unsigned short* __restrict__ kb,
                                            const unsigned short* __restrict__ vbt,
                                            unsigned short* __restrict__ ctxb) {
  __shared__ uint8_t Ks[64 * 256];
  __shared__ uint8_t Vs[128 * 128];
  __shared__ uint8_t Ps[4][16 * 128];
  const int qi = blockIdx.x, h = blockIdx.y, b = blockIdx.z;
  const int kvh = h >> 2;
  const int t0 = qi * 64;
  const int tid = threadIdx.x, lane = tid & 63, w = tid >> 6;

  bf16x8 qf[4];
  {
    int qrow = t0 + w * 16 + (lane & 15);
    const unsigned short* qp =
        qb + (size_t)(b * 2048 + qrow) * 2048 + h * 128 + (lane >> 4) * 8;
#pragma unroll
    for (int kc = 0; kc < 4; ++kc) qf[kc] = *(const bf16x8*)(qp + kc * 32);
  }
  f32x4 of[8];
#pragma unroll
  for (int i = 0; i < 8; ++i) of[i] = f32x4{0.f, 0.f, 0.f, 0.f};
  float m_run[4], l_run[4];
#pragma unroll
  for (int r = 0; r < 4; ++r) { m_run[r] = -1e30f; l_run[r] = 0.0f; }

  int kt0 = t0 - 512; if (kt0 < 0) kt0 = 0;
  const int nt = (t0 + 64 - kt0) >> 6;
  uint8_t* Pw = Ps[w];

  for (int it = 0; it < nt; ++it) {
    const int kt = kt0 + (it << 6);
    __syncthreads();
#pragma unroll
    for (int i = 0; i < 4; ++i) {
      int c = tid + 256 * i;
      int krow = c >> 4, kcin = c & 15;
      uint4 kv = *(const uint4*)(kb + (size_t)(b * 2048 + kt + krow) * 512 +
                                 kvh * 128 + kcin * 8);
      *(uint4*)(Ks + krow * 256 + ((kcin * 16) ^ ((krow & 7) << 4))) = kv;
      int vrow = c >> 3, vcin = c & 7;
      uint4 vv = *(const uint4*)(vbt + (size_t)(b * 512 + kvh * 128 + vrow) * 2048 +
                                 kt + vcin * 8);
      *(uint4*)(Vs + vrow * 128 + ((vcin * 16) ^ ((vrow & 7) << 4))) = vv;
    }
    __syncthreads();

    f32x4 sf[4];
#pragma unroll
    for (int nc = 0; nc < 4; ++nc) {
      f32x4 s = f32x4{0.f, 0.f, 0.f, 0.f};
      int key = nc * 16 + (lane & 15);
#pragma unroll
      for (int kc = 0; kc < 4; ++kc) {
        bf16x8 kf = *(const bf16x8*)(
            Ks + key * 256 + (((lane >> 4) * 16 + kc * 64) ^ ((key & 7) << 4)));
        s = __builtin_amdgcn_mfma_f32_16x16x32_bf16(qf[kc], kf, s, 0, 0, 0);
      }
      sf[nc] = s;
    }
#pragma unroll
    for (int nc = 0; nc < 4; ++nc) {
      int j = kt + nc * 16 + (lane & 15);
#pragma unroll
      for (int r = 0; r < 4; ++r) {
        int tq = t0 + w * 16 + (lane >> 4) * 4 + r;
        if (!((j <= tq) && (tq - j <= 512))) sf[nc][r] = -1e30f;
      }
    }
    float alpha[4];
#pragma unroll
    for (int r = 0; r < 4; ++r) {
      float mx = fmaxf(fmaxf(sf[0][r], sf[1][r]), fmaxf(sf[2][r], sf[3][r]));
      mx = fmaxf(mx, __shfl_xor(mx, 1));
      mx = fmaxf(mx, __shfl_xor(mx, 2));
      mx = fmaxf(mx, __shfl_xor(mx, 4));
      mx = fmaxf(mx, __shfl_xor(mx, 8));
      float mn = fmaxf(m_run[r], mx);
      alpha[r] = exp2f((m_run[r] - mn) * LOG2E);
      m_run[r] = mn;
    }
    float l_add[4] = {0.f, 0.f, 0.f, 0.f};
#pragma unroll
    for (int nc = 0; nc < 4; ++nc)
#pragma unroll
      for (int r = 0; r < 4; ++r) {
        float p = exp2f((sf[nc][r] - m_run[r]) * LOG2E);
        sf[nc][r] = p;
        l_add[r] += p;
      }
#pragma unroll
    for (int r = 0; r < 4; ++r) {
      float la = l_add[r];
      la += __shfl_xor(la, 1);
      la += __shfl_xor(la, 2);
      la += __shfl_xor(la, 4);
      la += __shfl_xor(la, 8);
      l_run[r] = l_run[r] * alpha[r] + la;
    }
#pragma unroll
    for (int i = 0; i < 8; ++i)
#pragma unroll
      for (int r = 0; r < 4; ++r) of[i][r] *= alpha[r];

#pragma unroll
    for (int nc = 0; nc < 4; ++nc) {
      int key = nc * 16 + (lane & 15);
#pragma unroll
      for (int r = 0; r < 4; ++r) {
        int prow = (lane >> 4) * 4 + r;
        *(unsigned short*)(Pw + prow * 128 + ((key * 2) ^ ((prow & 7) << 4))) =
            f2bf(sf[nc][r]);
      }
    }
#pragma unroll
    for (int ks = 0; ks < 2; ++ks) {
      int prow = lane & 15;
      bf16x8 pf = *(const bf16x8*)(
          Pw + prow * 128 + ((ks * 64 + (lane >> 4) * 16) ^ ((prow & 7) << 4)));
#pragma unroll
      for (int nc8 = 0; nc8 < 8; ++nc8) {
        int vrow = nc8 * 16 + (lane & 15);
        bf16x8 vf = *(const bf16x8*)(
            Vs + vrow * 128 + ((ks * 64 + (lane >> 4) * 16) ^ ((vrow & 7) << 4)));
        of[nc8] = __builtin_amdgcn_mfma_f32_16x16x32_bf16(pf, vf, of[nc8], 0, 0, 0);
      }
    }
  }
#pragma unroll
  for (int nc8 = 0; nc8 < 8; ++nc8)
#pragma unroll
    for (int r = 0; r < 4; ++r) {
      int tq = t0 + w * 16 + (lane >> 4) * 4 + r;
      int col = h * 128 + nc8 * 16 + (lane & 15);
      ctxb[(size_t)(b * 2048 + tq) * 2048 + col] = f2bf(of[nc8][r] / l_run[r]);
    }
}

// ---------------------------------------------------------------------------
extern "C" void kernel_launch(void* const* d_in, const int* in_sizes, int n_in,
                              void* d_out, int out_size, void* d_ws, size_t ws_size,
                              hipStream_t stream) {
  const float* x  = (const float*)d_in[0];   // [2,2048,2048]
  const float* Wq = (const float*)d_in[1];   // [2048,2048]
  const float* Wk = (const float*)d_in[2];   // [512,2048]
  const float* Wv = (const float*)d_in[3];   // [512,2048]
  const float* Wo = (const float*)d_in[4];   // [2048,2048]
  const float* qw = (const float*)d_in[5];   // [128]
  const float* kw = (const float*)d_in[6];   // [128]

  uint8_t* ws = (uint8_t*)d_ws;
  if (ws_size < 131072000ull) return;        // need ~125 MB scratch
  unsigned short* xb    = (unsigned short*)(ws);               // 16.8 MB
  unsigned short* wqkvb = (unsigned short*)(ws + 16777216);    // 12.6 MB
  unsigned short* wob   = (unsigned short*)(ws + 29360128);    //  8.4 MB
  float*          qkvf  = (float*)(ws + 37748736);             // 50.3 MB
  unsigned short* qb2   = (unsigned short*)(ws + 88080384);    // 16.8 MB
  unsigned short* kb2   = (unsigned short*)(ws + 104857600);   //  4.2 MB
  unsigned short* vbt   = (unsigned short*)(ws + 109051904);   //  4.2 MB
  unsigned short* ctxb  = (unsigned short*)(ws + 113246208);   // 16.8 MB
  float*          ropec = (float*)(ws + 130023424);            //  0.5 MB
  float*          ropes = (float*)(ws + 130547712);            //  0.5 MB

  // 1) all input casts to bf16 (one fused launch)
  castall<<<18432, 256, 0, stream>>>(x, Wq, Wk, Wv, Wo, xb, wqkvb, wob);
  // 2) rope table
  rope_tab<<<512, 256, 0, stream>>>(ropec, ropes);
  // 3) fused QKV GEMM: [4096,2048] x [3072,2048]^T -> fp32 [4096,3072]
  {
    dim3 g(3072 / 256, 4096 / 256);
    gemm256<256><<<g, 512, 0, stream>>>(xb, wqkvb, qkvf, 3072, 2048);
  }
  // 4) RMSNorm + RoPE + scale (Q, K)
  eplg<<<4096, 256, 0, stream>>>(qkvf, qw, kw, ropec, ropes, qb2, kb2);
  // 5) V transpose (tiled, coalesced)
  {
    dim3 g(32, 8, 2);
    vtrans<<<g, 256, 0, stream>>>(qkvf, vbt);
  }
  // 6) sliding-window attention
  {
    dim3 g(32, 16, 2);
    attn<<<g, 256, 0, stream>>>(qb2, kb2, vbt, ctxb);
  }
  // 7) output projection: [4096,2048] x [2048,2048]^T -> fp32 d_out
  {
    dim3 g(2048 / 128, 4096 / 256);
    gemm256<128><<<g, 512, 0, stream>>>(ctxb, wob, (float*)d_out, 2048, 2048);
  }
}

// Round 7
// 285.634 us; speedup vs baseline: 1.1447x; 1.0311x over previous
//
#include <hip/hip_runtime.h>
#include <stdint.h>

// ---------------------------------------------------------------------------
// Gemma3 block: QKV proj -> per-head RMSNorm -> RoPE -> sliding-window (512)
// causal attention -> out proj.  B=2, T=2048, D=2048, H=16, Hkv=4, Dh=128.
// R7: attention restructured for GQA sharing (4 Q-heads share one K/V staging,
// 256 blocks x 16 waves), K/V double-buffered via global_load_lds with counted
// vmcnt (T3/T4), defer-max (T13), LOG2E folded into Q scale (exp2 softmax).
// ---------------------------------------------------------------------------

typedef __attribute__((ext_vector_type(8))) short bf16x8;   // 8 bf16 = 4 VGPR
typedef __attribute__((ext_vector_type(4))) float f32x4;

typedef __attribute__((address_space(3))) unsigned int lds_u32;
typedef const __attribute__((address_space(1))) unsigned int glb_u32;

__device__ __forceinline__ unsigned short f2bf(float f) {
  unsigned int x = __builtin_bit_cast(unsigned int, f);
  x += 0x7FFFu + ((x >> 16) & 1u);            // round-nearest-even
  return (unsigned short)(x >> 16);
}

// ---- fused fp32 -> bf16 casts for all 5 inputs, float4-vectorized ----------
__global__ __launch_bounds__(256) void castall(const float* __restrict__ x,
                                               const float* __restrict__ wq,
                                               const float* __restrict__ wk,
                                               const float* __restrict__ wv,
                                               const float* __restrict__ wo,
                                               unsigned short* __restrict__ xb,
                                               unsigned short* __restrict__ wqkvb,
                                               unsigned short* __restrict__ wob) {
  int i = blockIdx.x * 256 + threadIdx.x;
  const float* src;
  unsigned short* dst;
  int off;
  if (i < 2097152)       { src = x;  dst = xb;              off = i; }
  else if (i < 3145728)  { src = wq; dst = wqkvb;           off = i - 2097152; }
  else if (i < 3407872)  { src = wk; dst = wqkvb + 4194304; off = i - 3145728; }
  else if (i < 3670016)  { src = wv; dst = wqkvb + 5242880; off = i - 3407872; }
  else                   { src = wo; dst = wob;             off = i - 3670016; }
  float4 v = ((const float4*)src)[off];
  uint2 o;
  o.x = (unsigned)f2bf(v.x) | ((unsigned)f2bf(v.y) << 16);
  o.y = (unsigned)f2bf(v.z) | ((unsigned)f2bf(v.w) << 16);
  ((uint2*)dst)[off] = o;
}

// ---- RoPE cos/sin table [T=2048][64] ---------------------------------------
__global__ __launch_bounds__(256) void rope_tab(float* __restrict__ c,
                                                float* __restrict__ s) {
  int idx = blockIdx.x * 256 + threadIdx.x;    // T*64 = 131072
  int t = idx >> 6, i = idx & 63;
  float invf = exp2f(-(float)i * (13.287712379549449f / 64.0f));
  float a = (float)t * invf;
  c[idx] = cosf(a);
  s[idx] = sinf(a);
}

// ---- bf16 GEMM, C[M,N] = A[M,K]*B[N,K]^T, fp32 out (R6-proven, unchanged) --
template <int BN>
__global__ __launch_bounds__(512, 2) void gemm256(const unsigned short* __restrict__ A,
                                                  const unsigned short* __restrict__ Bm,
                                                  float* __restrict__ C,
                                                  int N, int K) {
  constexpr int BSL = BN * 128;               // B slot bytes
  __shared__ uint8_t lds[65536 + 2 * BSL];    // [A0|A1|B0|B1]
  const int tid = threadIdx.x, lane = tid & 63, w = tid >> 6;
  const int wm = w >> 2, wn = w & 3;
  const size_t m0 = (size_t)blockIdx.y * 256, n0 = (size_t)blockIdx.x * BN;
  const int srow = lane >> 3;                 // row within 8-row wave segment
  const int schunk = (lane & 7) ^ srow;       // source 16B chunk (inv-swizzle)

  f32x4 acc[8][BN / 64];
#pragma unroll
  for (int i = 0; i < 8; ++i)
#pragma unroll
    for (int j = 0; j < BN / 64; ++j) acc[i][j] = f32x4{0.f, 0.f, 0.f, 0.f};

  const int NT = K >> 6;

  auto stageA = [&](int t, int par) {
    uint8_t* slot = lds + (par << 15);        // par * 32768
#pragma unroll
    for (int j = 0; j < 4; ++j) {             // 256 rows = 4 rounds x 64 rows
      int r0 = (j * 8 + w) * 8;
      const unsigned short* src =
          A + (m0 + r0 + srow) * (size_t)K + t * 64 + schunk * 8;
      __builtin_amdgcn_global_load_lds((glb_u32*)src,
                                       (lds_u32*)(slot + r0 * 128), 16, 0, 0);
    }
  };
  auto stageB = [&](int t, int par) {
    uint8_t* slot = lds + 65536 + par * BSL;
#pragma unroll
    for (int j = 0; j < BN / 64; ++j) {
      int r0 = (j * 8 + w) * 8;
      const unsigned short* src =
          Bm + (n0 + r0 + srow) * (size_t)K + t * 64 + schunk * 8;
      __builtin_amdgcn_global_load_lds((glb_u32*)src,
                                       (lds_u32*)(slot + r0 * 128), 16, 0, 0);
    }
  };
  auto compute = [&](int par, int h) {
    const uint8_t* Asl = lds + (par << 15);
    const uint8_t* Bsl = lds + 65536 + par * BSL;
    bf16x8 af[8], bf[BN / 64];
    const int x7 = lane & 7;
    const int cx = h * 4 + (lane >> 4);       // 16B chunk within 128B row
    const int rab = wm * 128 + (lane & 15);
    const int rbb = wn * (BN / 4) + (lane & 15);
#pragma unroll
    for (int mt = 0; mt < 8; ++mt)
      af[mt] = *(const bf16x8*)(Asl + (rab + mt * 16) * 128 + ((cx ^ x7) << 4));
#pragma unroll
    for (int nt = 0; nt < BN / 64; ++nt)
      bf[nt] = *(const bf16x8*)(Bsl + (rbb + nt * 16) * 128 + ((cx ^ x7) << 4));
    __builtin_amdgcn_s_setprio(1);
#pragma unroll
    for (int mt = 0; mt < 8; ++mt)
#pragma unroll
      for (int nt = 0; nt < BN / 64; ++nt)
        acc[mt][nt] = __builtin_amdgcn_mfma_f32_16x16x32_bf16(
            af[mt], bf[nt], acc[mt][nt], 0, 0, 0);
    __builtin_amdgcn_s_setprio(0);
  };

  stageA(0, 0);
  stageB(0, 0);
  for (int t = 0; t < NT - 1; ++t) {
    const int p = t & 1, q = p ^ 1;
    stageA(t + 1, q);
    asm volatile("s_waitcnt vmcnt(4)" ::: "memory");
    __builtin_amdgcn_s_barrier();
    __builtin_amdgcn_sched_barrier(0);        // keep reads after the barrier
    compute(p, 0);
    stageB(t + 1, q);
    compute(p, 1);
    asm volatile("" ::: "memory");
    __builtin_amdgcn_s_barrier();             // readers done before next stage
    __builtin_amdgcn_sched_barrier(0);
  }
  {
    const int p = (NT - 1) & 1;
    asm volatile("s_waitcnt vmcnt(0)" ::: "memory");
    __builtin_amdgcn_s_barrier();
    __builtin_amdgcn_sched_barrier(0);
    compute(p, 0);
    compute(p, 1);
  }
#pragma unroll
  for (int mt = 0; mt < 8; ++mt)
#pragma unroll
    for (int nt = 0; nt < BN / 64; ++nt) {
      size_t row = m0 + wm * 128 + mt * 16 + (lane >> 4) * 4;
      size_t col = n0 + wn * (BN / 4) + nt * 16 + (lane & 15);
#pragma unroll
      for (int r = 0; r < 4; ++r)
        C[(row + r) * N + col] = acc[mt][nt][r];
    }
}

// ---- RMSNorm + RoPE + scale epilogue (Q and K heads) -----------------------
// Q scale folds Dh^-0.5 * LOG2E so attention softmax uses exp2 directly.
__global__ __launch_bounds__(256) void eplg(const float* __restrict__ qkv,
                                            const float* __restrict__ qw,
                                            const float* __restrict__ kw,
                                            const float* __restrict__ rc,
                                            const float* __restrict__ rs,
                                            unsigned short* __restrict__ qb,
                                            unsigned short* __restrict__ kb) {
  const int row = blockIdx.x;                 // b*2048 + t
  const int t = row & 2047;
  const int lane = threadIdx.x & 63, w = threadIdx.x >> 6;
  const float* base = qkv + (size_t)row * 3072;
  const int d0 = 2 * lane;
  const float c0 = rc[t * 64 + (d0 & 63)];
  const float c1 = rc[t * 64 + ((d0 + 1) & 63)];
  const float s0 = rs[t * 64 + (d0 & 63)];
  const float s1 = rs[t * 64 + ((d0 + 1) & 63)];
  const float sgn = (lane < 32) ? -1.0f : 1.0f;   // rotate_half sign
  const float QS = 0.12751744817f;            // Dh^-0.5 * log2(e)

#pragma unroll
  for (int hh = 0; hh < 4; ++hh) {
    int h = w * 4 + hh;
    float2 x = *(const float2*)(base + h * 128 + d0);
    float ss = x.x * x.x + x.y * x.y;
#pragma unroll
    for (int m = 1; m < 64; m <<= 1) ss += __shfl_xor(ss, m);
    float r = rsqrtf(ss * (1.0f / 128.0f) + 1e-6f);
    float y0 = x.x * r * (1.0f + qw[d0]);
    float y1 = x.y * r * (1.0f + qw[d0 + 1]);
    float p0 = __shfl_xor(y0, 32);              // partner d +/- 64
    float p1 = __shfl_xor(y1, 32);
    float o0 = (y0 * c0 + sgn * p0 * s0) * QS;
    float o1 = (y1 * c1 + sgn * p1 * s1) * QS;
    unsigned int pk = (unsigned)f2bf(o0) | ((unsigned)f2bf(o1) << 16);
    *(unsigned int*)(qb + (size_t)row * 2048 + h * 128 + d0) = pk;
  }
  {
    float2 x = *(const float2*)(base + 2048 + w * 128 + d0);
    float ss = x.x * x.x + x.y * x.y;
#pragma unroll
    for (int m = 1; m < 64; m <<= 1) ss += __shfl_xor(ss, m);
    float r = rsqrtf(ss * (1.0f / 128.0f) + 1e-6f);
    float y0 = x.x * r * (1.0f + kw[d0]);
    float y1 = x.y * r * (1.0f + kw[d0 + 1]);
    float p0 = __shfl_xor(y0, 32);
    float p1 = __shfl_xor(y1, 32);
    float o0 = y0 * c0 + sgn * p0 * s0;
    float o1 = y1 * c1 + sgn * p1 * s1;
    unsigned int pk = (unsigned)f2bf(o0) | ((unsigned)f2bf(o1) << 16);
    *(unsigned int*)(kb + (size_t)row * 512 + w * 128 + d0) = pk;
  }
}

// ---- V transpose: qkvf v-cols -> vbt[b*512 + d][t] bf16, 64x64 LDS tiles ---
__global__ __launch_bounds__(256) void vtrans(const float* __restrict__ qkvf,
                                              unsigned short* __restrict__ vbt) {
  __shared__ float tile[64][65];               // +1 pad: conflict-free
  const int t0 = blockIdx.x * 64;
  const int d0 = blockIdx.y * 64;
  const int b = blockIdx.z;
  const int tid = threadIdx.x;
#pragma unroll
  for (int i = 0; i < 4; ++i) {
    int idx = tid + 256 * i;                   // 0..1023
    int r = idx >> 4, c4 = idx & 15;
    float4 v = *(const float4*)(qkvf + (size_t)(b * 2048 + t0 + r) * 3072 +
                                2560 + d0 + c4 * 4);
    tile[r][c4 * 4 + 0] = v.x;
    tile[r][c4 * 4 + 1] = v.y;
    tile[r][c4 * 4 + 2] = v.z;
    tile[r][c4 * 4 + 3] = v.w;
  }
  __syncthreads();
  const int dr = tid >> 2, ts = (tid & 3) * 16;
  unsigned short tmp[16];
#pragma unroll
  for (int j = 0; j < 16; ++j) tmp[j] = f2bf(tile[ts + j][dr]);
  uint4* dst = (uint4*)(vbt + (size_t)(b * 512 + d0 + dr) * 2048 + t0 + ts);
  dst[0] = *(uint4*)(tmp);
  dst[1] = *(uint4*)(tmp + 8);
}

// ---- flash attention, sliding window 512, GQA-shared -----------------------
// Grid (32 qtiles of 64 rows, 4 kvh, 2 b) = 256 blocks, 1024 thr = 16 waves.
// Wave w: head = kvh*4 + (w&3), q rows t0 + (w>>2)*16 .. +15.
// K/V double-buffered, staged once per block for all 4 heads via
// global_load_lds (source-side swizzle), counted vmcnt(2) pipeline.
__global__ __launch_bounds__(1024) void attn(const unsigned short* __restrict__ qb,
                                             const unsigned short* __restrict__ kb,
                                             const unsigned short* __restrict__ vbt,
                                             unsigned short* __restrict__ ctxb) {
  __shared__ uint8_t Ks[2][64 * 256];   // 64 keys x 128 bf16 (256B row), swz
  __shared__ uint8_t Vs[2][128 * 128];  // 128 dims x 64 keys (128B row), swz
  __shared__ uint8_t Ps[16][16 * 128];  // per-wave P: 16 rows x 64 bf16, swz
  const int qi = blockIdx.x, kvh = blockIdx.y, b = blockIdx.z;
  const int t0 = qi * 64;
  const int tid = threadIdx.x, lane = tid & 63, w = tid >> 6;
  const int h = kvh * 4 + (w & 3), wq = w >> 2;

  // Q fragments in registers (A-operand: row = lane&15, k = (lane>>4)*8..)
  bf16x8 qf[4];
  {
    int qrow = t0 + wq * 16 + (lane & 15);
    const unsigned short* qp =
        qb + (size_t)(b * 2048 + qrow) * 2048 + h * 128 + (lane >> 4) * 8;
#pragma unroll
    for (int kc = 0; kc < 4; ++kc) qf[kc] = *(const bf16x8*)(qp + kc * 32);
  }
  f32x4 of[8];
#pragma unroll
  for (int i = 0; i < 8; ++i) of[i] = f32x4{0.f, 0.f, 0.f, 0.f};
  float m_run[4], l_run[4];
#pragma unroll
  for (int r = 0; r < 4; ++r) { m_run[r] = -1e30f; l_run[r] = 0.0f; }

  int kt0 = t0 - 512; if (kt0 < 0) kt0 = 0;
  const int nt = (t0 + 64 - kt0) >> 6;          // <= 9 key tiles
  uint8_t* Pw = Ps[w];

  // staging: one 16B K-chunk + one 16B V-chunk per thread per tile.
  // LDS dest linear (wave base + lane*16); st-swizzle applied to the
  // per-lane GLOBAL chunk (slot s of row r holds global chunk s^(r&7)).
  const int krow_s = 4 * w + (lane >> 4);       // K row this lane covers
  const int kchunk_s = (lane & 15) ^ (krow_s & 7);
  const int vrow_s = 8 * w + (lane >> 3);       // V row this lane covers
  const int vchunk_s = (lane & 7) ^ (vrow_s & 7);
  auto stage = [&](int it, int par) {
    int kt = kt0 + (it << 6);
    const unsigned short* ksrc =
        kb + (size_t)(b * 2048 + kt + krow_s) * 512 + kvh * 128 + kchunk_s * 8;
    __builtin_amdgcn_global_load_lds((glb_u32*)ksrc,
                                     (lds_u32*)(&Ks[par][w * 1024]), 16, 0, 0);
    const unsigned short* vsrc =
        vbt + (size_t)(b * 512 + kvh * 128 + vrow_s) * 2048 + kt + vchunk_s * 8;
    __builtin_amdgcn_global_load_lds((glb_u32*)vsrc,
                                     (lds_u32*)(&Vs[par][w * 1024]), 16, 0, 0);
  };

  stage(0, 0);
  for (int it = 0; it < nt; ++it) {
    const int par = it & 1;
    const int kt = kt0 + (it << 6);
    if (it + 1 < nt) {
      stage(it + 1, par ^ 1);
      asm volatile("s_waitcnt vmcnt(2)" ::: "memory");  // tile it landed
    } else {
      asm volatile("s_waitcnt vmcnt(0)" ::: "memory");
    }
    __builtin_amdgcn_s_barrier();
    __builtin_amdgcn_sched_barrier(0);

    // S = Q K^T : 16 q-rows x 64 keys per wave (scores in log2 domain)
    f32x4 sf[4];
#pragma unroll
    for (int nc = 0; nc < 4; ++nc) {
      f32x4 s = f32x4{0.f, 0.f, 0.f, 0.f};
      int key = nc * 16 + (lane & 15);
#pragma unroll
      for (int kc = 0; kc < 4; ++kc) {
        bf16x8 kf = *(const bf16x8*)(
            Ks[par] + key * 256 + (((lane >> 4) * 16 + kc * 64) ^ ((key & 7) << 4)));
        s = __builtin_amdgcn_mfma_f32_16x16x32_bf16(qf[kc], kf, s, 0, 0, 0);
      }
      sf[nc] = s;
    }
    // mask: j <= t and t - j <= 512
#pragma unroll
    for (int nc = 0; nc < 4; ++nc) {
      int j = kt + nc * 16 + (lane & 15);
#pragma unroll
      for (int r = 0; r < 4; ++r) {
        int tq = t0 + wq * 16 + (lane >> 4) * 4 + r;
        if (!((j <= tq) && (tq - j <= 512))) sf[nc][r] = -1e30f;
      }
    }
    // online softmax (16-lane groups hold one row's 16 keys); defer-max T13
    float mx[4];
#pragma unroll
    for (int r = 0; r < 4; ++r) {
      float m = fmaxf(fmaxf(sf[0][r], sf[1][r]), fmaxf(sf[2][r], sf[3][r]));
      m = fmaxf(m, __shfl_xor(m, 1));
      m = fmaxf(m, __shfl_xor(m, 2));
      m = fmaxf(m, __shfl_xor(m, 4));
      m = fmaxf(m, __shfl_xor(m, 8));
      mx[r] = m;
    }
    bool grow = (mx[0] > m_run[0] + 8.0f) | (mx[1] > m_run[1] + 8.0f) |
                (mx[2] > m_run[2] + 8.0f) | (mx[3] > m_run[3] + 8.0f);
    if (__any(grow)) {                       // rescale path (rare after tile 0)
      float alpha[4];
#pragma unroll
      for (int r = 0; r < 4; ++r) {
        float mn = fmaxf(m_run[r], mx[r]);
        alpha[r] = exp2f(m_run[r] - mn);
        m_run[r] = mn;
        l_run[r] *= alpha[r];
      }
#pragma unroll
      for (int i = 0; i < 8; ++i)
#pragma unroll
        for (int r = 0; r < 4; ++r) of[i][r] *= alpha[r];
    }
    float l_add[4] = {0.f, 0.f, 0.f, 0.f};
#pragma unroll
    for (int nc = 0; nc < 4; ++nc)
#pragma unroll
      for (int r = 0; r < 4; ++r) {
        float p = exp2f(sf[nc][r] - m_run[r]);   // bounded by 2^8
        sf[nc][r] = p;
        l_add[r] += p;
      }
#pragma unroll
    for (int r = 0; r < 4; ++r) {
      float la = l_add[r];
      la += __shfl_xor(la, 1);
      la += __shfl_xor(la, 2);
      la += __shfl_xor(la, 4);
      la += __shfl_xor(la, 8);
      l_run[r] += la;
    }
    // P -> LDS (per-wave, bf16, swizzled) to repack into A-operand layout
#pragma unroll
    for (int nc = 0; nc < 4; ++nc) {
      int key = nc * 16 + (lane & 15);
#pragma unroll
      for (int r = 0; r < 4; ++r) {
        int prow = (lane >> 4) * 4 + r;
        *(unsigned short*)(Pw + prow * 128 + ((key * 2) ^ ((prow & 7) << 4))) =
            f2bf(sf[nc][r]);
      }
    }
    // O += P V
#pragma unroll
    for (int ks = 0; ks < 2; ++ks) {
      int prow = lane & 15;
      bf16x8 pf = *(const bf16x8*)(
          Pw + prow * 128 + ((ks * 64 + (lane >> 4) * 16) ^ ((prow & 7) << 4)));
#pragma unroll
      for (int nc8 = 0; nc8 < 8; ++nc8) {
        int vrow = nc8 * 16 + (lane & 15);
        bf16x8 vf = *(const bf16x8*)(
            Vs[par] + vrow * 128 + ((ks * 64 + (lane >> 4) * 16) ^ ((vrow & 7) << 4)));
        of[nc8] = __builtin_amdgcn_mfma_f32_16x16x32_bf16(pf, vf, of[nc8], 0, 0, 0);
      }
    }
    asm volatile("" ::: "memory");
    __builtin_amdgcn_s_barrier();             // readers done before overwrite
    __builtin_amdgcn_sched_barrier(0);
  }
  // normalize + store ctx (bf16, row-major [B*T][H*Dh])
#pragma unroll
  for (int nc8 = 0; nc8 < 8; ++nc8)
#pragma unroll
    for (int r = 0; r < 4; ++r) {
      int tq = t0 + wq * 16 + (lane >> 4) * 4 + r;
      int col = h * 128 + nc8 * 16 + (lane & 15);
      ctxb[(size_t)(b * 2048 + tq) * 2048 + col] = f2bf(of[nc8][r] / l_run[r]);
    }
}

// ---------------------------------------------------------------------------
extern "C" void kernel_launch(void* const* d_in, const int* in_sizes, int n_in,
                              void* d_out, int out_size, void* d_ws, size_t ws_size,
                              hipStream_t stream) {
  const float* x  = (const float*)d_in[0];   // [2,2048,2048]
  const float* Wq = (const float*)d_in[1];   // [2048,2048]
  const float* Wk = (const float*)d_in[2];   // [512,2048]
  const float* Wv = (const float*)d_in[3];   // [512,2048]
  const float* Wo = (const float*)d_in[4];   // [2048,2048]
  const float* qw = (const float*)d_in[5];   // [128]
  const float* kw = (const float*)d_in[6];   // [128]

  uint8_t* ws = (uint8_t*)d_ws;
  if (ws_size < 131072000ull) return;        // need ~125 MB scratch
  unsigned short* xb    = (unsigned short*)(ws);               // 16.8 MB
  unsigned short* wqkvb = (unsigned short*)(ws + 16777216);    // 12.6 MB
  unsigned short* wob   = (unsigned short*)(ws + 29360128);    //  8.4 MB
  float*          qkvf  = (float*)(ws + 37748736);             // 50.3 MB
  unsigned short* qb2   = (unsigned short*)(ws + 88080384);    // 16.8 MB
  unsigned short* kb2   = (unsigned short*)(ws + 104857600);   //  4.2 MB
  unsigned short* vbt   = (unsigned short*)(ws + 109051904);   //  4.2 MB
  unsigned short* ctxb  = (unsigned short*)(ws + 113246208);   // 16.8 MB
  float*          ropec = (float*)(ws + 130023424);            //  0.5 MB
  float*          ropes = (float*)(ws + 130547712);            //  0.5 MB

  // 1) all input casts to bf16 (one fused launch)
  castall<<<18432, 256, 0, stream>>>(x, Wq, Wk, Wv, Wo, xb, wqkvb, wob);
  // 2) rope table
  rope_tab<<<512, 256, 0, stream>>>(ropec, ropes);
  // 3) fused QKV GEMM: [4096,2048] x [3072,2048]^T -> fp32 [4096,3072]
  {
    dim3 g(3072 / 256, 4096 / 256);
    gemm256<256><<<g, 512, 0, stream>>>(xb, wqkvb, qkvf, 3072, 2048);
  }
  // 4) RMSNorm + RoPE + scale (Q, K)
  eplg<<<4096, 256, 0, stream>>>(qkvf, qw, kw, ropec, ropes, qb2, kb2);
  // 5) V transpose (tiled, coalesced)
  {
    dim3 g(32, 8, 2);
    vtrans<<<g, 256, 0, stream>>>(qkvf, vbt);
  }
  // 6) sliding-window attention (GQA-shared)
  {
    dim3 g(32, 4, 2);
    attn<<<g, 1024, 0, stream>>>(qb2, kb2, vbt, ctxb);
  }
  // 7) output projection: [4096,2048] x [2048,2048]^T -> fp32 d_out
  {
    dim3 g(2048 / 128, 4096 / 256);
    gemm256<128><<<g, 512, 0, stream>>>(ctxb, wob, (float*)d_out, 2048, 2048);
  }
}